// Round 1
// baseline (706.951 us; speedup 1.0000x reference)
//
#include <hip/hip_runtime.h>
#include <cstdint>
#include <cstddef>

#define D_MODEL 1024
#define SEQ     4096
#define BATCH   4
#define M_ROWS  (BATCH*SEQ)   // 16384
#define NCHUNK  64
#define LCHUNK  (SEQ/NCHUNK)  // 64

typedef __bf16 bf16_t;
typedef __bf16 bf16x8 __attribute__((ext_vector_type(8)));
typedef __bf16 bf16x4 __attribute__((ext_vector_type(4)));
typedef float  f32x4  __attribute__((ext_vector_type(4)));

// ---------------------------------------------------------------- utilities
__device__ __forceinline__ void load_lds_128(const bf16_t* g, bf16_t* l) {
    __builtin_amdgcn_global_load_lds(
        (const __attribute__((address_space(1))) unsigned int*)g,
        (__attribute__((address_space(3))) unsigned int*)l,
        16, 0, 0);
}

__device__ __forceinline__ float2 bf16pair_to_f2(unsigned int u) {
    union { unsigned int i; float f; } a, b;
    a.i = u << 16;          // low element
    b.i = u & 0xffff0000u;  // high element
    float2 r; r.x = a.f; r.y = b.f; return r;
}

// ---------------------------------------------------- weight convert+transpose
// in: f32 (R,C) row-major  ->  out: bf16 (C,R) row-major
__global__ __launch_bounds__(256)
void transpose_to_bf16(const float* __restrict__ in, bf16_t* __restrict__ out,
                       int R, int C) {
    __shared__ float t[32][33];
    int tx = threadIdx.x & 31, ty = threadIdx.x >> 5;   // 32 x 8
    int c0 = blockIdx.x * 32, r0 = blockIdx.y * 32;
    #pragma unroll
    for (int j = 0; j < 32; j += 8)
        t[ty + j][tx] = in[(size_t)(r0 + ty + j) * C + c0 + tx];
    __syncthreads();
    #pragma unroll
    for (int j = 0; j < 32; j += 8)
        out[(size_t)(c0 + ty + j) * R + r0 + tx] = (bf16_t)t[tx][ty + j];
}

// ---------------------------------------------------------------- layernorm
// one block per row; 256 threads x float4 = 1024 elements
__global__ __launch_bounds__(256)
void ln_kernel(const float* __restrict__ x, const float* __restrict__ gamma,
               const float* __restrict__ beta, bf16_t* __restrict__ h) {
    int row = blockIdx.x;
    int tid = threadIdx.x;
    const float4* xr = (const float4*)(x + (size_t)row * D_MODEL);
    float4 v = xr[tid];
    float s  = v.x + v.y + v.z + v.w;
    float ss = v.x*v.x + v.y*v.y + v.z*v.z + v.w*v.w;
    #pragma unroll
    for (int off = 32; off; off >>= 1) {
        s  += __shfl_down(s, off);
        ss += __shfl_down(ss, off);
    }
    __shared__ float red[8];
    int wave = tid >> 6, lane = tid & 63;
    if (lane == 0) { red[wave] = s; red[4 + wave] = ss; }
    __syncthreads();
    if (tid == 0) {
        float S  = red[0] + red[1] + red[2] + red[3];
        float SS = red[4] + red[5] + red[6] + red[7];
        float mean = S * (1.0f / D_MODEL);
        float var  = SS * (1.0f / D_MODEL) - mean * mean;
        red[0] = mean;
        red[1] = rsqrtf(var + 1e-5f);
    }
    __syncthreads();
    float mean = red[0], rstd = red[1];
    float4 gv = ((const float4*)gamma)[tid];
    float4 bv = ((const float4*)beta)[tid];
    bf16x4 o;
    o[0] = (bf16_t)((v.x - mean) * rstd * gv.x + bv.x);
    o[1] = (bf16_t)((v.y - mean) * rstd * gv.y + bv.y);
    o[2] = (bf16_t)((v.z - mean) * rstd * gv.z + bv.z);
    o[3] = (bf16_t)((v.w - mean) * rstd * gv.w + bv.w);
    ((bf16x4*)h)[(size_t)row * (D_MODEL / 4) + tid] = o;
}

// ---------------------------------------------------------------- GEMM
// A: bf16 (M,K) row-major.  Bt: bf16 (N,K) row-major (i.e. B transposed).
// MODE 0: out_bf16 = sigmoid(acc + bias)
// MODE 1: out_bf16 = acc + bias
// MODE 2: out_bf16 = gelu_exact(acc + bias)
// MODE 3: out_f32  = xres + acc + bias
template <int MODE>
__global__ __launch_bounds__(256, 2)
void gemm_kernel(const bf16_t* __restrict__ A, const bf16_t* __restrict__ Bt,
                 const float* __restrict__ bias, const float* __restrict__ xres,
                 void* __restrict__ out, int M, int N, int K) {
    __shared__ __align__(16) bf16_t ldsA[128 * 32];
    __shared__ __align__(16) bf16_t ldsB[128 * 32];

    const int tid  = threadIdx.x;
    const int lane = tid & 63;
    const int wave = tid >> 6;
    const int wm   = wave & 1;   // 2x2 wave grid, each wave 64x64
    const int wn   = wave >> 1;

    const int m0 = blockIdx.x * 128;
    const int n0 = blockIdx.y * 128;

    f32x4 acc[4][4];
    f32x4 zero = {0.f, 0.f, 0.f, 0.f};
    #pragma unroll
    for (int i = 0; i < 4; i++)
        #pragma unroll
        for (int j = 0; j < 4; j++) acc[i][j] = zero;

    const int rowInChunk = lane >> 2;        // 0..15
    const int colBlk     = (lane & 3) * 8;   // 0,8,16,24
    const int quad = lane >> 4;
    const int l16  = lane & 15;

    for (int k0 = 0; k0 < K; k0 += 32) {
        __syncthreads();
        // stage 128x32 A-tile and 128x32 B-tile; 8 chunks of 16 rows each,
        // wave w covers chunks w and w+4 (1 KiB per wave-issue, 16 B/lane)
        #pragma unroll
        for (int r = 0; r < 2; r++) {
            int chunk = r * 4 + wave;
            int arow = m0 + chunk * 16 + rowInChunk;
            load_lds_128(A + (size_t)arow * K + k0 + colBlk,
                         ldsA + chunk * 512 + lane * 8);
            int brow = n0 + chunk * 16 + rowInChunk;
            load_lds_128(Bt + (size_t)brow * K + k0 + colBlk,
                         ldsB + chunk * 512 + lane * 8);
        }
        __syncthreads();

        bf16x8 af[4], bfr[4];
        #pragma unroll
        for (int mt = 0; mt < 4; mt++)
            af[mt] = *(const bf16x8*)(ldsA + (wm * 64 + mt * 16 + l16) * 32 + quad * 8);
        #pragma unroll
        for (int nt = 0; nt < 4; nt++)
            bfr[nt] = *(const bf16x8*)(ldsB + (wn * 64 + nt * 16 + l16) * 32 + quad * 8);
        #pragma unroll
        for (int mt = 0; mt < 4; mt++)
            #pragma unroll
            for (int nt = 0; nt < 4; nt++)
                acc[mt][nt] = __builtin_amdgcn_mfma_f32_16x16x32_bf16(
                    af[mt], bfr[nt], acc[mt][nt], 0, 0, 0);
    }

    // epilogue: C/D layout col=lane&15, row=(lane>>4)*4+reg
    #pragma unroll
    for (int mt = 0; mt < 4; mt++) {
        #pragma unroll
        for (int nt = 0; nt < 4; nt++) {
            int col = n0 + wn * 64 + nt * 16 + l16;
            float bv = bias[col];
            #pragma unroll
            for (int r = 0; r < 4; r++) {
                int row = m0 + wm * 64 + mt * 16 + quad * 4 + r;
                size_t oidx = (size_t)row * N + col;
                float val = acc[mt][nt][r] + bv;
                if (MODE == 0) {
                    val = 1.0f / (1.0f + __expf(-val));
                    ((bf16_t*)out)[oidx] = (bf16_t)val;
                } else if (MODE == 1) {
                    ((bf16_t*)out)[oidx] = (bf16_t)val;
                } else if (MODE == 2) {
                    val = 0.5f * val * (1.0f + erff(val * 0.70710678118654752f));
                    ((bf16_t*)out)[oidx] = (bf16_t)val;
                } else {
                    ((float*)out)[oidx] = xres[oidx] + val;
                }
            }
        }
    }
}

// ---------------------------------------------------------------- scan
// phase A: per-chunk sums of g and g*v.  grid = BATCH*NCHUNK*(D/512),
// 256 threads, 2 d's per thread.
__global__ __launch_bounds__(256)
void scan_partial(const bf16_t* __restrict__ g, const bf16_t* __restrict__ v,
                  float* __restrict__ sg, float* __restrict__ sgv) {
    int dt = blockIdx.x & 1;
    int c  = (blockIdx.x >> 1) & (NCHUNK - 1);
    int b  = blockIdx.x >> 7;
    int d  = dt * 512 + threadIdx.x * 2;
    float s0 = 0.f, s1 = 0.f, t0 = 0.f, t1 = 0.f;
    for (int i = 0; i < LCHUNK; i++) {
        int s = c * LCHUNK + i;
        size_t idx = ((size_t)(b * SEQ + s)) * D_MODEL + d;
        float2 gf = bf16pair_to_f2(*(const unsigned int*)(g + idx));
        float2 vf = bf16pair_to_f2(*(const unsigned int*)(v + idx));
        s0 += gf.x; s1 += gf.y;
        t0 += gf.x * vf.x; t1 += gf.y * vf.y;
    }
    size_t o = ((size_t)(b * NCHUNK + c)) * D_MODEL + d;
    sg[o] = s0;  sg[o + 1] = s1;
    sgv[o] = t0; sgv[o + 1] = t1;
}

// phase B: in-place exclusive prefix over chunks per (b,d).  2048 threads.
__global__ __launch_bounds__(256)
void scan_prefix(float* __restrict__ sg, float* __restrict__ sgv) {
    int gid = blockIdx.x * 256 + threadIdx.x;  // 0..2047
    int b = gid >> 9;
    int d = (gid & 511) * 2;
    float rg0 = 0.f, rg1 = 0.f, rv0 = 0.f, rv1 = 0.f;
    for (int c = 0; c < NCHUNK; c++) {
        size_t o = ((size_t)(b * NCHUNK + c)) * D_MODEL + d;
        float a0 = sg[o], a1 = sg[o + 1];
        sg[o] = rg0; sg[o + 1] = rg1;
        rg0 += a0; rg1 += a1;
        float b0 = sgv[o], b1 = sgv[o + 1];
        sgv[o] = rv0; sgv[o + 1] = rv1;
        rv0 += b0; rv1 += b1;
    }
}

// phase C: apply — x_new = x + cumsum(g*v)/(cumsum(g)+eps), written to out
__global__ __launch_bounds__(256)
void scan_apply(const bf16_t* __restrict__ g, const bf16_t* __restrict__ v,
                const float* __restrict__ x, const float* __restrict__ sg,
                const float* __restrict__ sgv, float* __restrict__ out) {
    int dt = blockIdx.x & 1;
    int c  = (blockIdx.x >> 1) & (NCHUNK - 1);
    int b  = blockIdx.x >> 7;
    int d  = dt * 512 + threadIdx.x * 2;
    size_t o = ((size_t)(b * NCHUNK + c)) * D_MODEL + d;
    float rg0 = sg[o], rg1 = sg[o + 1];
    float rv0 = sgv[o], rv1 = sgv[o + 1];
    for (int i = 0; i < LCHUNK; i++) {
        int s = c * LCHUNK + i;
        size_t idx = ((size_t)(b * SEQ + s)) * D_MODEL + d;
        float2 gf = bf16pair_to_f2(*(const unsigned int*)(g + idx));
        float2 vf = bf16pair_to_f2(*(const unsigned int*)(v + idx));
        rv0 += gf.x * vf.x; rg0 += gf.x;
        rv1 += gf.y * vf.y; rg1 += gf.y;
        float2 xv = *(const float2*)(x + idx);
        float2 ov;
        ov.x = xv.x + rv0 / (rg0 + 1e-6f);
        ov.y = xv.y + rv1 / (rg1 + 1e-6f);
        *(float2*)(out + idx) = ov;
    }
}

// ---------------------------------------------------------------- launcher
extern "C" void kernel_launch(void* const* d_in, const int* in_sizes, int n_in,
                              void* d_out, int out_size, void* d_ws, size_t ws_size,
                              hipStream_t stream) {
    (void)in_sizes; (void)n_in; (void)out_size; (void)ws_size;
    const float* x       = (const float*)d_in[0];
    const float* ln1_g   = (const float*)d_in[1];
    const float* ln1_b   = (const float*)d_in[2];
    const float* ln2_g   = (const float*)d_in[3];
    const float* ln2_b   = (const float*)d_in[4];
    const float* gate_w  = (const float*)d_in[5];
    const float* gate_b  = (const float*)d_in[6];
    const float* value_w = (const float*)d_in[7];
    const float* value_b = (const float*)d_in[8];
    const float* ffn_w1  = (const float*)d_in[9];
    const float* ffn_b1  = (const float*)d_in[10];
    const float* ffn_w2  = (const float*)d_in[11];
    const float* ffn_b2  = (const float*)d_in[12];
    float* out = (float*)d_out;

    char* ws = (char*)d_ws;
    const size_t MB = 1024 * 1024;
    bf16_t* wg_t = (bf16_t*)(ws + 0 * MB);      // (1024,1024) bf16   2 MB
    bf16_t* wv_t = (bf16_t*)(ws + 2 * MB);      // (1024,1024) bf16   2 MB
    bf16_t* w1_t = (bf16_t*)(ws + 4 * MB);      // (4096,1024) bf16   8 MB
    bf16_t* w2_t = (bf16_t*)(ws + 12 * MB);     // (1024,4096) bf16   8 MB
    bf16_t* h    = (bf16_t*)(ws + 20 * MB);     // (16384,1024) bf16 32 MB (reused as h2)
    bf16_t* g    = (bf16_t*)(ws + 52 * MB);     // (16384,1024) bf16 32 MB
    bf16_t* v    = (bf16_t*)(ws + 84 * MB);     // (16384,1024) bf16 32 MB
    float*  sg   = (float*)(ws + 116 * MB);     // (4,64,1024) f32    1 MB
    float*  sgv  = (float*)(ws + 117 * MB);     // (4,64,1024) f32    1 MB
    bf16_t* act  = (bf16_t*)(ws + 118 * MB);    // (16384,4096) bf16 128 MB

    // 1. weight convert+transpose to bf16 (N,K)
    transpose_to_bf16<<<dim3(32, 32), 256, 0, stream>>>(gate_w, wg_t, 1024, 1024);
    transpose_to_bf16<<<dim3(32, 32), 256, 0, stream>>>(value_w, wv_t, 1024, 1024);
    transpose_to_bf16<<<dim3(128, 32), 256, 0, stream>>>(ffn_w1, w1_t, 1024, 4096);
    transpose_to_bf16<<<dim3(32, 128), 256, 0, stream>>>(ffn_w2, w2_t, 4096, 1024);

    // 2. h = LN1(x)
    ln_kernel<<<M_ROWS, 256, 0, stream>>>(x, ln1_g, ln1_b, h);

    // 3. g = sigmoid(h@gate_w + gate_b); v = h@value_w + value_b
    gemm_kernel<0><<<dim3(M_ROWS / 128, 1024 / 128), 256, 0, stream>>>(
        h, wg_t, gate_b, nullptr, g, M_ROWS, 1024, 1024);
    gemm_kernel<1><<<dim3(M_ROWS / 128, 1024 / 128), 256, 0, stream>>>(
        h, wv_t, value_b, nullptr, v, M_ROWS, 1024, 1024);

    // 4. x_new = x + cumsum(g*v)/(cumsum(g)+eps)  -> d_out
    scan_partial<<<BATCH * NCHUNK * 2, 256, 0, stream>>>(g, v, sg, sgv);
    scan_prefix<<<8, 256, 0, stream>>>(sg, sgv);
    scan_apply<<<BATCH * NCHUNK * 2, 256, 0, stream>>>(g, v, x, sg, sgv, out);

    // 5. h2 = LN2(x_new)
    ln_kernel<<<M_ROWS, 256, 0, stream>>>(out, ln2_g, ln2_b, h);

    // 6. act = gelu(h2@ffn_w1 + ffn_b1)
    gemm_kernel<2><<<dim3(M_ROWS / 128, 4096 / 128), 256, 0, stream>>>(
        h, w1_t, ffn_b1, nullptr, act, M_ROWS, 4096, 1024);

    // 7. out = x_new + act@ffn_w2 + ffn_b2   (reads and rewrites d_out)
    gemm_kernel<3><<<dim3(M_ROWS / 128, 1024 / 128), 256, 0, stream>>>(
        act, w2_t, ffn_b2, out, out, M_ROWS, 1024, 4096);
}

// Round 2
// 679.787 us; speedup vs baseline: 1.0400x; 1.0400x over previous
//
#include <hip/hip_runtime.h>
#include <cstdint>
#include <cstddef>

#define D_MODEL 1024
#define SEQ     4096
#define BATCH   4
#define M_ROWS  (BATCH*SEQ)   // 16384
#define NCHUNK  64
#define LCHUNK  (SEQ/NCHUNK)  // 64

typedef __bf16 bf16_t;
typedef __bf16 bf16x8 __attribute__((ext_vector_type(8)));
typedef __bf16 bf16x4 __attribute__((ext_vector_type(4)));
typedef float  f32x4  __attribute__((ext_vector_type(4)));

// ---------------------------------------------------------------- utilities
__device__ __forceinline__ void load_lds_128(const bf16_t* g, bf16_t* l) {
    __builtin_amdgcn_global_load_lds(
        (const __attribute__((address_space(1))) unsigned int*)g,
        (__attribute__((address_space(3))) unsigned int*)l,
        16, 0, 0);
}

__device__ __forceinline__ float2 bf16pair_to_f2(unsigned int u) {
    union { unsigned int i; float f; } a, b;
    a.i = u << 16;          // low element
    b.i = u & 0xffff0000u;  // high element
    float2 r; r.x = a.f; r.y = b.f; return r;
}

// ---------------------------------------------- fused weight convert+transpose
// all four weights in one launch; in: f32 (R,C) row-major -> out: bf16 (C,R)
__global__ __launch_bounds__(256)
void transpose_all(const float* __restrict__ gate_w, const float* __restrict__ value_w,
                   const float* __restrict__ ffn_w1, const float* __restrict__ ffn_w2,
                   bf16_t* __restrict__ wgv_t, bf16_t* __restrict__ w1_t,
                   bf16_t* __restrict__ w2_t) {
    int id = blockIdx.x;
    const float* in; bf16_t* outp; int R, C, bx, by;
    if (id < 1024)      { in = gate_w;  outp = wgv_t;               R = 1024; C = 1024; bx = id & 31;  by = id >> 5; }
    else if (id < 2048) { id -= 1024; in = value_w; outp = wgv_t + 1024*1024; R = 1024; C = 1024; bx = id & 31;  by = id >> 5; }
    else if (id < 6144) { id -= 2048; in = ffn_w1;  outp = w1_t;    R = 1024; C = 4096; bx = id & 127; by = id >> 7; }
    else                { id -= 6144; in = ffn_w2;  outp = w2_t;    R = 4096; C = 1024; bx = id & 31;  by = id >> 5; }
    __shared__ float t[32][33];
    int tx = threadIdx.x & 31, ty = threadIdx.x >> 5;   // 32 x 8
    int c0 = bx * 32, r0 = by * 32;
    #pragma unroll
    for (int j = 0; j < 32; j += 8)
        t[ty + j][tx] = in[(size_t)(r0 + ty + j) * C + c0 + tx];
    __syncthreads();
    #pragma unroll
    for (int j = 0; j < 32; j += 8)
        outp[(size_t)(c0 + ty + j) * R + r0 + tx] = (bf16_t)t[tx][ty + j];
}

// ---------------------------------------------------------------- layernorm
__global__ __launch_bounds__(256)
void ln_kernel(const float* __restrict__ x, const float* __restrict__ gamma,
               const float* __restrict__ beta, bf16_t* __restrict__ h) {
    int row = blockIdx.x;
    int tid = threadIdx.x;
    const float4* xr = (const float4*)(x + (size_t)row * D_MODEL);
    float4 v = xr[tid];
    float s  = v.x + v.y + v.z + v.w;
    float ss = v.x*v.x + v.y*v.y + v.z*v.z + v.w*v.w;
    #pragma unroll
    for (int off = 32; off; off >>= 1) {
        s  += __shfl_down(s, off);
        ss += __shfl_down(ss, off);
    }
    __shared__ float red[8];
    int wave = tid >> 6, lane = tid & 63;
    if (lane == 0) { red[wave] = s; red[4 + wave] = ss; }
    __syncthreads();
    if (tid == 0) {
        float S  = red[0] + red[1] + red[2] + red[3];
        float SS = red[4] + red[5] + red[6] + red[7];
        float mean = S * (1.0f / D_MODEL);
        float var  = SS * (1.0f / D_MODEL) - mean * mean;
        red[0] = mean;
        red[1] = rsqrtf(var + 1e-5f);
    }
    __syncthreads();
    float mean = red[0], rstd = red[1];
    float4 gv = ((const float4*)gamma)[tid];
    float4 bv = ((const float4*)beta)[tid];
    bf16x4 o;
    o[0] = (bf16_t)((v.x - mean) * rstd * gv.x + bv.x);
    o[1] = (bf16_t)((v.y - mean) * rstd * gv.y + bv.y);
    o[2] = (bf16_t)((v.z - mean) * rstd * gv.z + bv.z);
    o[3] = (bf16_t)((v.w - mean) * rstd * gv.w + bv.w);
    ((bf16x4*)h)[(size_t)row * (D_MODEL / 4) + tid] = o;
}

// ---------------------------------------------------------------- GEMM
// A: bf16 (M,K) row-major.  Bt: bf16 (N,K) row-major.
// BK=64, XOR-swizzled LDS (granule = chunk^(row&7), 16B granules) -> no bank
// conflicts; swizzle applied on the GLOBAL source address because
// global_load_lds forces LDS dst = base + lane*16.
// MFMA operands swapped (bfr as A-op, af as B-op) so each lane's 4 acc values
// are 4 CONSECUTIVE n at one m -> vectorized epilogue stores.
// MODE 2: out_bf16 = gelu_exact(acc + bias)
// MODE 3: out_f32  = xres + acc + bias
// MODE 4: fused gate/value: n<1024 -> out=sigmoid(acc+bias); n>=1024 ->
//         out2 = acc + bias2  (both (M,1024) bf16)
template <int MODE>
__global__ __launch_bounds__(256, 2)
void gemm_kernel(const bf16_t* __restrict__ A, const bf16_t* __restrict__ Bt,
                 const float* __restrict__ bias, const float* __restrict__ bias2,
                 const float* __restrict__ xres,
                 void* __restrict__ out, void* __restrict__ out2,
                 int M, int N, int K) {
    __shared__ __align__(16) bf16_t ldsA[128 * 64];   // 16 KiB
    __shared__ __align__(16) bf16_t ldsB[128 * 64];   // 16 KiB

    const int tid  = threadIdx.x;
    const int lane = tid & 63;
    const int wave = tid >> 6;
    const int wm   = wave & 1;   // 2x2 wave grid, each wave 64x64
    const int wn   = wave >> 1;

    const int m0 = blockIdx.x * 128;
    const int n0 = blockIdx.y * 128;

    f32x4 acc[4][4];
    f32x4 zero = {0.f, 0.f, 0.f, 0.f};
    #pragma unroll
    for (int i = 0; i < 4; i++)
        #pragma unroll
        for (int j = 0; j < 4; j++) acc[i][j] = zero;

    // staging: each issue covers 8 rows x 64 cols (8 lanes/row, 16B chunks)
    const int rl     = lane >> 3;            // row within 8-row group
    const int srcCol = ((lane & 7) ^ rl) * 8; // swizzled source col (bf16 units)

    const int quad = lane >> 4;
    const int l16  = lane & 15;
    const int rswz = l16 & 7;                // row&7 for frag reads

    for (int k0 = 0; k0 < K; k0 += 64) {
        __syncthreads();
        #pragma unroll
        for (int i = 0; i < 4; i++) {
            int cb = i * 4 + wave;           // 16 groups of 8 rows
            int r  = cb * 8 + rl;
            load_lds_128(A  + (size_t)(m0 + r) * K + k0 + srcCol,
                         ldsA + cb * 512 + lane * 8);
            load_lds_128(Bt + (size_t)(n0 + r) * K + k0 + srcCol,
                         ldsB + cb * 512 + lane * 8);
        }
        __syncthreads();

        #pragma unroll
        for (int kk = 0; kk < 2; kk++) {
            int pos = ((quad + 4 * kk) ^ rswz) * 8;
            bf16x8 af[4], bfr[4];
            #pragma unroll
            for (int mt = 0; mt < 4; mt++)
                af[mt] = *(const bf16x8*)(ldsA + (wm * 64 + mt * 16 + l16) * 64 + pos);
            #pragma unroll
            for (int nt = 0; nt < 4; nt++)
                bfr[nt] = *(const bf16x8*)(ldsB + (wn * 64 + nt * 16 + l16) * 64 + pos);
            #pragma unroll
            for (int mt = 0; mt < 4; mt++)
                #pragma unroll
                for (int nt = 0; nt < 4; nt++)
                    acc[mt][nt] = __builtin_amdgcn_mfma_f32_16x16x32_bf16(
                        bfr[nt], af[mt], acc[mt][nt], 0, 0, 0);
        }
    }

    // epilogue: lane holds C[m0+wm*64+mt*16+l16][n0+wn*64+nt*16+quad*4 + r]
    #pragma unroll
    for (int mt = 0; mt < 4; mt++) {
        int row = m0 + wm * 64 + mt * 16 + l16;
        #pragma unroll
        for (int nt = 0; nt < 4; nt++) {
            int col = n0 + wn * 64 + nt * 16 + quad * 4;
            f32x4 a = acc[mt][nt];
            if (MODE == 4) {
                bool isV = (n0 >= 1024);         // block-uniform
                int c1 = col & 1023;
                float4 bv = *(const float4*)((isV ? bias2 : bias) + c1);
                float4 val;
                val.x = a[0] + bv.x; val.y = a[1] + bv.y;
                val.z = a[2] + bv.z; val.w = a[3] + bv.w;
                if (!isV) {
                    val.x = 1.0f / (1.0f + __expf(-val.x));
                    val.y = 1.0f / (1.0f + __expf(-val.y));
                    val.z = 1.0f / (1.0f + __expf(-val.z));
                    val.w = 1.0f / (1.0f + __expf(-val.w));
                }
                bf16x4 p;
                p[0] = (bf16_t)val.x; p[1] = (bf16_t)val.y;
                p[2] = (bf16_t)val.z; p[3] = (bf16_t)val.w;
                bf16_t* o = (bf16_t*)(isV ? out2 : out);
                *(bf16x4*)(o + (size_t)row * 1024 + c1) = p;
            } else if (MODE == 2) {
                float4 bv = *(const float4*)(bias + col);
                float4 val;
                val.x = a[0] + bv.x; val.y = a[1] + bv.y;
                val.z = a[2] + bv.z; val.w = a[3] + bv.w;
                val.x = 0.5f * val.x * (1.0f + erff(val.x * 0.70710678118654752f));
                val.y = 0.5f * val.y * (1.0f + erff(val.y * 0.70710678118654752f));
                val.z = 0.5f * val.z * (1.0f + erff(val.z * 0.70710678118654752f));
                val.w = 0.5f * val.w * (1.0f + erff(val.w * 0.70710678118654752f));
                bf16x4 p;
                p[0] = (bf16_t)val.x; p[1] = (bf16_t)val.y;
                p[2] = (bf16_t)val.z; p[3] = (bf16_t)val.w;
                *(bf16x4*)((bf16_t*)out + (size_t)row * N + col) = p;
            } else { // MODE 3
                float4 bv = *(const float4*)(bias + col);
                float4 xr = *(const float4*)(xres + (size_t)row * N + col);
                float4 val;
                val.x = xr.x + a[0] + bv.x; val.y = xr.y + a[1] + bv.y;
                val.z = xr.z + a[2] + bv.z; val.w = xr.w + a[3] + bv.w;
                *(float4*)((float*)out + (size_t)row * N + col) = val;
            }
        }
    }
}

// ---------------------------------------------------------------- scan
// phase A: per-chunk sums of g and g*v
__global__ __launch_bounds__(256)
void scan_partial(const bf16_t* __restrict__ g, const bf16_t* __restrict__ v,
                  float* __restrict__ sg, float* __restrict__ sgv) {
    int dt = blockIdx.x & 1;
    int c  = (blockIdx.x >> 1) & (NCHUNK - 1);
    int b  = blockIdx.x >> 7;
    int d  = dt * 512 + threadIdx.x * 2;
    float s0 = 0.f, s1 = 0.f, t0 = 0.f, t1 = 0.f;
    for (int i = 0; i < LCHUNK; i++) {
        int s = c * LCHUNK + i;
        size_t idx = ((size_t)(b * SEQ + s)) * D_MODEL + d;
        float2 gf = bf16pair_to_f2(*(const unsigned int*)(g + idx));
        float2 vf = bf16pair_to_f2(*(const unsigned int*)(v + idx));
        s0 += gf.x; s1 += gf.y;
        t0 += gf.x * vf.x; t1 += gf.y * vf.y;
    }
    size_t o = ((size_t)(b * NCHUNK + c)) * D_MODEL + d;
    sg[o] = s0;  sg[o + 1] = s1;
    sgv[o] = t0; sgv[o + 1] = t1;
}

// phase B+C fused: each block sums partials of chunks < c (2 MB, L2-resident),
// then applies x_new = x + cumsum(g*v)/(cumsum(g)+eps)
__global__ __launch_bounds__(256)
void scan_apply(const bf16_t* __restrict__ g, const bf16_t* __restrict__ v,
                const float* __restrict__ x, const float* __restrict__ sg,
                const float* __restrict__ sgv, float* __restrict__ out) {
    int dt = blockIdx.x & 1;
    int c  = (blockIdx.x >> 1) & (NCHUNK - 1);
    int b  = blockIdx.x >> 7;
    int d  = dt * 512 + threadIdx.x * 2;
    float rg0 = 0.f, rg1 = 0.f, rv0 = 0.f, rv1 = 0.f;
    for (int p = 0; p < c; p++) {
        size_t o = ((size_t)(b * NCHUNK + p)) * D_MODEL + d;
        float2 a  = *(const float2*)(sg + o);
        float2 bb = *(const float2*)(sgv + o);
        rg0 += a.x;  rg1 += a.y;
        rv0 += bb.x; rv1 += bb.y;
    }
    for (int i = 0; i < LCHUNK; i++) {
        int s = c * LCHUNK + i;
        size_t idx = ((size_t)(b * SEQ + s)) * D_MODEL + d;
        float2 gf = bf16pair_to_f2(*(const unsigned int*)(g + idx));
        float2 vf = bf16pair_to_f2(*(const unsigned int*)(v + idx));
        rv0 += gf.x * vf.x; rg0 += gf.x;
        rv1 += gf.y * vf.y; rg1 += gf.y;
        float2 xv = *(const float2*)(x + idx);
        float2 ov;
        ov.x = xv.x + rv0 / (rg0 + 1e-6f);
        ov.y = xv.y + rv1 / (rg1 + 1e-6f);
        *(float2*)(out + idx) = ov;
    }
}

// ---------------------------------------------------------------- launcher
extern "C" void kernel_launch(void* const* d_in, const int* in_sizes, int n_in,
                              void* d_out, int out_size, void* d_ws, size_t ws_size,
                              hipStream_t stream) {
    (void)in_sizes; (void)n_in; (void)out_size; (void)ws_size;
    const float* x       = (const float*)d_in[0];
    const float* ln1_g   = (const float*)d_in[1];
    const float* ln1_b   = (const float*)d_in[2];
    const float* ln2_g   = (const float*)d_in[3];
    const float* ln2_b   = (const float*)d_in[4];
    const float* gate_w  = (const float*)d_in[5];
    const float* gate_b  = (const float*)d_in[6];
    const float* value_w = (const float*)d_in[7];
    const float* value_b = (const float*)d_in[8];
    const float* ffn_w1  = (const float*)d_in[9];
    const float* ffn_b1  = (const float*)d_in[10];
    const float* ffn_w2  = (const float*)d_in[11];
    const float* ffn_b2  = (const float*)d_in[12];
    float* out = (float*)d_out;

    char* ws = (char*)d_ws;
    const size_t MB = 1024 * 1024;
    bf16_t* wgv_t = (bf16_t*)(ws + 0 * MB);     // (2048,1024) bf16   4 MB
    bf16_t* w1_t  = (bf16_t*)(ws + 4 * MB);     // (4096,1024) bf16   8 MB
    bf16_t* w2_t  = (bf16_t*)(ws + 12 * MB);    // (1024,4096) bf16   8 MB
    bf16_t* h     = (bf16_t*)(ws + 20 * MB);    // (16384,1024) bf16 32 MB (reused as h2)
    bf16_t* g     = (bf16_t*)(ws + 52 * MB);    // (16384,1024) bf16 32 MB
    bf16_t* v     = (bf16_t*)(ws + 84 * MB);    // (16384,1024) bf16 32 MB
    float*  sg    = (float*)(ws + 116 * MB);    // (4,64,1024) f32    1 MB
    float*  sgv   = (float*)(ws + 117 * MB);    // (4,64,1024) f32    1 MB
    bf16_t* act   = (bf16_t*)(ws + 118 * MB);   // (16384,4096) bf16 128 MB

    // 1. all weight transposes in one launch
    transpose_all<<<10240, 256, 0, stream>>>(gate_w, value_w, ffn_w1, ffn_w2,
                                             wgv_t, w1_t, w2_t);

    // 2. h = LN1(x)
    ln_kernel<<<M_ROWS, 256, 0, stream>>>(x, ln1_g, ln1_b, h);

    // 3. fused: g = sigmoid(h@gate_w + gate_b); v = h@value_w + value_b
    gemm_kernel<4><<<dim3(M_ROWS / 128, 2048 / 128), 256, 0, stream>>>(
        h, wgv_t, gate_b, value_b, nullptr, g, v, M_ROWS, 2048, 1024);

    // 4. x_new = x + cumsum(g*v)/(cumsum(g)+eps)  -> d_out
    scan_partial<<<BATCH * NCHUNK * 2, 256, 0, stream>>>(g, v, sg, sgv);
    scan_apply<<<BATCH * NCHUNK * 2, 256, 0, stream>>>(g, v, x, sg, sgv, out);

    // 5. h2 = LN2(x_new)
    ln_kernel<<<M_ROWS, 256, 0, stream>>>(out, ln2_g, ln2_b, h);

    // 6. act = gelu(h2@ffn_w1 + ffn_b1)
    gemm_kernel<2><<<dim3(M_ROWS / 128, 4096 / 128), 256, 0, stream>>>(
        h, w1_t, ffn_b1, nullptr, nullptr, act, nullptr, M_ROWS, 4096, 1024);

    // 7. out = x_new + act@ffn_w2 + ffn_b2
    gemm_kernel<3><<<dim3(M_ROWS / 128, 1024 / 128), 256, 0, stream>>>(
        act, w2_t, ffn_b2, nullptr, out, out, nullptr, M_ROWS, 1024, 4096);
}

// Round 3
// 661.455 us; speedup vs baseline: 1.0688x; 1.0277x over previous
//
#include <hip/hip_runtime.h>
#include <cstdint>
#include <cstddef>

#define D_MODEL 1024
#define SEQ     4096
#define BATCH   4
#define M_ROWS  (BATCH*SEQ)   // 16384
#define NCHUNK  64
#define LCHUNK  (SEQ/NCHUNK)  // 64

typedef __bf16 bf16_t;
typedef __bf16 bf16x8 __attribute__((ext_vector_type(8)));
typedef __bf16 bf16x4 __attribute__((ext_vector_type(4)));
typedef float  f32x4  __attribute__((ext_vector_type(4)));

// ---------------------------------------------------------------- utilities
__device__ __forceinline__ void load_lds_128(const bf16_t* g, bf16_t* l) {
    __builtin_amdgcn_global_load_lds(
        (const __attribute__((address_space(1))) unsigned int*)g,
        (__attribute__((address_space(3))) unsigned int*)l,
        16, 0, 0);
}

__device__ __forceinline__ float2 bf16pair_to_f2(unsigned int u) {
    union { unsigned int i; float f; } a, b;
    a.i = u << 16;          // low element
    b.i = u & 0xffff0000u;  // high element
    float2 r; r.x = a.f; r.y = b.f; return r;
}

// ---------------------------------------------- fused weight convert+transpose
// all four weights in one launch; in: f32 (R,C) row-major -> out: bf16 (C,R)
__global__ __launch_bounds__(256)
void transpose_all(const float* __restrict__ gate_w, const float* __restrict__ value_w,
                   const float* __restrict__ ffn_w1, const float* __restrict__ ffn_w2,
                   bf16_t* __restrict__ wgv_t, bf16_t* __restrict__ w1_t,
                   bf16_t* __restrict__ w2_t) {
    int id = blockIdx.x;
    const float* in; bf16_t* outp; int R, C, bx, by;
    if (id < 1024)      { in = gate_w;  outp = wgv_t;               R = 1024; C = 1024; bx = id & 31;  by = id >> 5; }
    else if (id < 2048) { id -= 1024; in = value_w; outp = wgv_t + 1024*1024; R = 1024; C = 1024; bx = id & 31;  by = id >> 5; }
    else if (id < 6144) { id -= 2048; in = ffn_w1;  outp = w1_t;    R = 1024; C = 4096; bx = id & 127; by = id >> 7; }
    else                { id -= 6144; in = ffn_w2;  outp = w2_t;    R = 4096; C = 1024; bx = id & 31;  by = id >> 5; }
    __shared__ float t[32][33];
    int tx = threadIdx.x & 31, ty = threadIdx.x >> 5;   // 32 x 8
    int c0 = bx * 32, r0 = by * 32;
    #pragma unroll
    for (int j = 0; j < 32; j += 8)
        t[ty + j][tx] = in[(size_t)(r0 + ty + j) * C + c0 + tx];
    __syncthreads();
    #pragma unroll
    for (int j = 0; j < 32; j += 8)
        outp[(size_t)(c0 + ty + j) * R + r0 + tx] = (bf16_t)t[tx][ty + j];
}

// ---------------------------------------------------------------- layernorm
__global__ __launch_bounds__(256)
void ln_kernel(const float* __restrict__ x, const float* __restrict__ gamma,
               const float* __restrict__ beta, bf16_t* __restrict__ h) {
    int row = blockIdx.x;
    int tid = threadIdx.x;
    const float4* xr = (const float4*)(x + (size_t)row * D_MODEL);
    float4 v = xr[tid];
    float s  = v.x + v.y + v.z + v.w;
    float ss = v.x*v.x + v.y*v.y + v.z*v.z + v.w*v.w;
    #pragma unroll
    for (int off = 32; off; off >>= 1) {
        s  += __shfl_down(s, off);
        ss += __shfl_down(ss, off);
    }
    __shared__ float red[8];
    int wave = tid >> 6, lane = tid & 63;
    if (lane == 0) { red[wave] = s; red[4 + wave] = ss; }
    __syncthreads();
    if (tid == 0) {
        float S  = red[0] + red[1] + red[2] + red[3];
        float SS = red[4] + red[5] + red[6] + red[7];
        float mean = S * (1.0f / D_MODEL);
        float var  = SS * (1.0f / D_MODEL) - mean * mean;
        red[0] = mean;
        red[1] = rsqrtf(var + 1e-5f);
    }
    __syncthreads();
    float mean = red[0], rstd = red[1];
    float4 gv = ((const float4*)gamma)[tid];
    float4 bv = ((const float4*)beta)[tid];
    bf16x4 o;
    o[0] = (bf16_t)((v.x - mean) * rstd * gv.x + bv.x);
    o[1] = (bf16_t)((v.y - mean) * rstd * gv.y + bv.y);
    o[2] = (bf16_t)((v.z - mean) * rstd * gv.z + bv.z);
    o[3] = (bf16_t)((v.w - mean) * rstd * gv.w + bv.w);
    ((bf16x4*)h)[(size_t)row * (D_MODEL / 4) + tid] = o;
}

// ---------------------------------------------------------------- GEMM
// A: bf16 (M,K) row-major.  Bt: bf16 (N,K) row-major.
// Grid is N-MAJOR: blockIdx.x = n-tile (consecutive blocks share the A-tile,
// B stays L2/L3-resident), blockIdx.y = m-tile.
// BK=64, XOR-swizzled LDS staging (zero bank conflicts, verified r2).
// MFMA operands swapped so each lane's 4 acc values are 4 consecutive n.
// __launch_bounds__(256,4): cap unified regs at 128/wave -> 4 blocks/CU
// (r2's 132 regs gave 3 blocks/CU -> 3+1 grid quantization on ffn2).
// MODE 2: out_bf16 = gelu_exact(acc + bias)
// MODE 3: out_f32  = xres + acc + bias
// MODE 4: fused gate/value: n<1024 -> sigmoid(acc+bias) -> out; else acc+bias2 -> out2
template <int MODE>
__global__ __launch_bounds__(256, 4)
void gemm_kernel(const bf16_t* __restrict__ A, const bf16_t* __restrict__ Bt,
                 const float* __restrict__ bias, const float* __restrict__ bias2,
                 const float* __restrict__ xres,
                 void* __restrict__ out, void* __restrict__ out2,
                 int M, int N, int K) {
    __shared__ __align__(16) bf16_t ldsA[128 * 64];   // 16 KiB
    __shared__ __align__(16) bf16_t ldsB[128 * 64];   // 16 KiB

    const int tid  = threadIdx.x;
    const int lane = tid & 63;
    const int wave = tid >> 6;
    const int wm   = wave & 1;   // 2x2 wave grid, each wave 64x64
    const int wn   = wave >> 1;

    const int n0 = blockIdx.x * 128;
    const int m0 = blockIdx.y * 128;

    f32x4 acc[4][4];
    f32x4 zero = {0.f, 0.f, 0.f, 0.f};
    #pragma unroll
    for (int i = 0; i < 4; i++)
        #pragma unroll
        for (int j = 0; j < 4; j++) acc[i][j] = zero;

    // staging: each issue covers 8 rows x 64 cols (8 lanes/row, 16B chunks)
    const int rl     = lane >> 3;             // row within 8-row group
    const int srcCol = ((lane & 7) ^ rl) * 8; // swizzled source col (bf16 units)

    const int quad = lane >> 4;
    const int l16  = lane & 15;
    const int rswz = l16 & 7;                 // row&7 for frag reads

    for (int k0 = 0; k0 < K; k0 += 64) {
        __syncthreads();
        #pragma unroll
        for (int i = 0; i < 4; i++) {
            int cb = i * 4 + wave;            // 16 groups of 8 rows
            int r  = cb * 8 + rl;
            load_lds_128(A  + (size_t)(m0 + r) * K + k0 + srcCol,
                         ldsA + cb * 512 + lane * 8);
            load_lds_128(Bt + (size_t)(n0 + r) * K + k0 + srcCol,
                         ldsB + cb * 512 + lane * 8);
        }
        __syncthreads();

        #pragma unroll
        for (int kk = 0; kk < 2; kk++) {
            int pos = ((quad + 4 * kk) ^ rswz) * 8;
            bf16x8 af[4], bfr[4];
            #pragma unroll
            for (int mt = 0; mt < 4; mt++)
                af[mt] = *(const bf16x8*)(ldsA + (wm * 64 + mt * 16 + l16) * 64 + pos);
            #pragma unroll
            for (int nt = 0; nt < 4; nt++)
                bfr[nt] = *(const bf16x8*)(ldsB + (wn * 64 + nt * 16 + l16) * 64 + pos);
            #pragma unroll
            for (int mt = 0; mt < 4; mt++)
                #pragma unroll
                for (int nt = 0; nt < 4; nt++)
                    acc[mt][nt] = __builtin_amdgcn_mfma_f32_16x16x32_bf16(
                        bfr[nt], af[mt], acc[mt][nt], 0, 0, 0);
        }
    }

    // epilogue: lane holds C[m0+wm*64+mt*16+l16][n0+wn*64+nt*16+quad*4 + r]
    #pragma unroll
    for (int mt = 0; mt < 4; mt++) {
        int row = m0 + wm * 64 + mt * 16 + l16;
        #pragma unroll
        for (int nt = 0; nt < 4; nt++) {
            int col = n0 + wn * 64 + nt * 16 + quad * 4;
            f32x4 a = acc[mt][nt];
            if (MODE == 4) {
                bool isV = (n0 >= 1024);         // block-uniform
                int c1 = col & 1023;
                float4 bv = *(const float4*)((isV ? bias2 : bias) + c1);
                float4 val;
                val.x = a[0] + bv.x; val.y = a[1] + bv.y;
                val.z = a[2] + bv.z; val.w = a[3] + bv.w;
                if (!isV) {
                    val.x = 1.0f / (1.0f + __expf(-val.x));
                    val.y = 1.0f / (1.0f + __expf(-val.y));
                    val.z = 1.0f / (1.0f + __expf(-val.z));
                    val.w = 1.0f / (1.0f + __expf(-val.w));
                }
                bf16x4 p;
                p[0] = (bf16_t)val.x; p[1] = (bf16_t)val.y;
                p[2] = (bf16_t)val.z; p[3] = (bf16_t)val.w;
                bf16_t* o = (bf16_t*)(isV ? out2 : out);
                *(bf16x4*)(o + (size_t)row * 1024 + c1) = p;
            } else if (MODE == 2) {
                float4 bv = *(const float4*)(bias + col);
                float4 val;
                val.x = a[0] + bv.x; val.y = a[1] + bv.y;
                val.z = a[2] + bv.z; val.w = a[3] + bv.w;
                val.x = 0.5f * val.x * (1.0f + erff(val.x * 0.70710678118654752f));
                val.y = 0.5f * val.y * (1.0f + erff(val.y * 0.70710678118654752f));
                val.z = 0.5f * val.z * (1.0f + erff(val.z * 0.70710678118654752f));
                val.w = 0.5f * val.w * (1.0f + erff(val.w * 0.70710678118654752f));
                bf16x4 p;
                p[0] = (bf16_t)val.x; p[1] = (bf16_t)val.y;
                p[2] = (bf16_t)val.z; p[3] = (bf16_t)val.w;
                *(bf16x4*)((bf16_t*)out + (size_t)row * N + col) = p;
            } else { // MODE 3
                float4 bv = *(const float4*)(bias + col);
                float4 xr = *(const float4*)(xres + (size_t)row * N + col);
                float4 val;
                val.x = xr.x + a[0] + bv.x; val.y = xr.y + a[1] + bv.y;
                val.z = xr.z + a[2] + bv.z; val.w = xr.w + a[3] + bv.w;
                *(float4*)((float*)out + (size_t)row * N + col) = val;
            }
        }
    }
}

// ---------------------------------------------------------------- scan
// phase A: per-chunk sums of g and g*v
__global__ __launch_bounds__(256)
void scan_partial(const bf16_t* __restrict__ g, const bf16_t* __restrict__ v,
                  float* __restrict__ sg, float* __restrict__ sgv) {
    int dt = blockIdx.x & 1;
    int c  = (blockIdx.x >> 1) & (NCHUNK - 1);
    int b  = blockIdx.x >> 7;
    int d  = dt * 512 + threadIdx.x * 2;
    float s0 = 0.f, s1 = 0.f, t0 = 0.f, t1 = 0.f;
    for (int i = 0; i < LCHUNK; i++) {
        int s = c * LCHUNK + i;
        size_t idx = ((size_t)(b * SEQ + s)) * D_MODEL + d;
        float2 gf = bf16pair_to_f2(*(const unsigned int*)(g + idx));
        float2 vf = bf16pair_to_f2(*(const unsigned int*)(v + idx));
        s0 += gf.x; s1 += gf.y;
        t0 += gf.x * vf.x; t1 += gf.y * vf.y;
    }
    size_t o = ((size_t)(b * NCHUNK + c)) * D_MODEL + d;
    sg[o] = s0;  sg[o + 1] = s1;
    sgv[o] = t0; sgv[o + 1] = t1;
}

// phase B+C fused: each block sums partials of chunks < c (2 MB, L2-resident),
// then applies x_new = x + cumsum(g*v)/(cumsum(g)+eps)
__global__ __launch_bounds__(256)
void scan_apply(const bf16_t* __restrict__ g, const bf16_t* __restrict__ v,
                const float* __restrict__ x, const float* __restrict__ sg,
                const float* __restrict__ sgv, float* __restrict__ out) {
    int dt = blockIdx.x & 1;
    int c  = (blockIdx.x >> 1) & (NCHUNK - 1);
    int b  = blockIdx.x >> 7;
    int d  = dt * 512 + threadIdx.x * 2;
    float rg0 = 0.f, rg1 = 0.f, rv0 = 0.f, rv1 = 0.f;
    for (int p = 0; p < c; p++) {
        size_t o = ((size_t)(b * NCHUNK + p)) * D_MODEL + d;
        float2 a  = *(const float2*)(sg + o);
        float2 bb = *(const float2*)(sgv + o);
        rg0 += a.x;  rg1 += a.y;
        rv0 += bb.x; rv1 += bb.y;
    }
    for (int i = 0; i < LCHUNK; i++) {
        int s = c * LCHUNK + i;
        size_t idx = ((size_t)(b * SEQ + s)) * D_MODEL + d;
        float2 gf = bf16pair_to_f2(*(const unsigned int*)(g + idx));
        float2 vf = bf16pair_to_f2(*(const unsigned int*)(v + idx));
        rv0 += gf.x * vf.x; rg0 += gf.x;
        rv1 += gf.y * vf.y; rg1 += gf.y;
        float2 xv = *(const float2*)(x + idx);
        float2 ov;
        ov.x = xv.x + rv0 / (rg0 + 1e-6f);
        ov.y = xv.y + rv1 / (rg1 + 1e-6f);
        *(float2*)(out + idx) = ov;
    }
}

// ---------------------------------------------------------------- launcher
extern "C" void kernel_launch(void* const* d_in, const int* in_sizes, int n_in,
                              void* d_out, int out_size, void* d_ws, size_t ws_size,
                              hipStream_t stream) {
    (void)in_sizes; (void)n_in; (void)out_size; (void)ws_size;
    const float* x       = (const float*)d_in[0];
    const float* ln1_g   = (const float*)d_in[1];
    const float* ln1_b   = (const float*)d_in[2];
    const float* ln2_g   = (const float*)d_in[3];
    const float* ln2_b   = (const float*)d_in[4];
    const float* gate_w  = (const float*)d_in[5];
    const float* gate_b  = (const float*)d_in[6];
    const float* value_w = (const float*)d_in[7];
    const float* value_b = (const float*)d_in[8];
    const float* ffn_w1  = (const float*)d_in[9];
    const float* ffn_b1  = (const float*)d_in[10];
    const float* ffn_w2  = (const float*)d_in[11];
    const float* ffn_b2  = (const float*)d_in[12];
    float* out = (float*)d_out;

    char* ws = (char*)d_ws;
    const size_t MB = 1024 * 1024;
    bf16_t* wgv_t = (bf16_t*)(ws + 0 * MB);     // (2048,1024) bf16   4 MB
    bf16_t* w1_t  = (bf16_t*)(ws + 4 * MB);     // (4096,1024) bf16   8 MB
    bf16_t* w2_t  = (bf16_t*)(ws + 12 * MB);    // (1024,4096) bf16   8 MB
    bf16_t* h     = (bf16_t*)(ws + 20 * MB);    // (16384,1024) bf16 32 MB (reused as h2)
    bf16_t* g     = (bf16_t*)(ws + 52 * MB);    // (16384,1024) bf16 32 MB
    bf16_t* v     = (bf16_t*)(ws + 84 * MB);    // (16384,1024) bf16 32 MB
    float*  sg    = (float*)(ws + 116 * MB);    // (4,64,1024) f32    1 MB
    float*  sgv   = (float*)(ws + 117 * MB);    // (4,64,1024) f32    1 MB
    bf16_t* act   = (bf16_t*)(ws + 118 * MB);   // (16384,4096) bf16 128 MB

    // 1. all weight transposes in one launch
    transpose_all<<<10240, 256, 0, stream>>>(gate_w, value_w, ffn_w1, ffn_w2,
                                             wgv_t, w1_t, w2_t);

    // 2. h = LN1(x)
    ln_kernel<<<M_ROWS, 256, 0, stream>>>(x, ln1_g, ln1_b, h);

    // 3. fused: g = sigmoid(h@gate_w + gate_b); v = h@value_w + value_b
    gemm_kernel<4><<<dim3(2048 / 128, M_ROWS / 128), 256, 0, stream>>>(
        h, wgv_t, gate_b, value_b, nullptr, g, v, M_ROWS, 2048, 1024);

    // 4. x_new = x + cumsum(g*v)/(cumsum(g)+eps)  -> d_out
    scan_partial<<<BATCH * NCHUNK * 2, 256, 0, stream>>>(g, v, sg, sgv);
    scan_apply<<<BATCH * NCHUNK * 2, 256, 0, stream>>>(g, v, x, sg, sgv, out);

    // 5. h2 = LN2(x_new)
    ln_kernel<<<M_ROWS, 256, 0, stream>>>(out, ln2_g, ln2_b, h);

    // 6. act = gelu(h2@ffn_w1 + ffn_b1)
    gemm_kernel<2><<<dim3(4096 / 128, M_ROWS / 128), 256, 0, stream>>>(
        h, w1_t, ffn_b1, nullptr, nullptr, act, nullptr, M_ROWS, 4096, 1024);

    // 7. out = x_new + act@ffn_w2 + ffn_b2
    gemm_kernel<3><<<dim3(1024 / 128, M_ROWS / 128), 256, 0, stream>>>(
        act, w2_t, ffn_b2, nullptr, out, out, nullptr, M_ROWS, 1024, 4096);
}

// Round 4
// 631.682 us; speedup vs baseline: 1.1192x; 1.0471x over previous
//
#include <hip/hip_runtime.h>
#include <cstdint>
#include <cstddef>

#define D_MODEL 1024
#define SEQ     4096
#define BATCH   4
#define M_ROWS  (BATCH*SEQ)   // 16384
#define NCHUNK  64
#define LCHUNK  (SEQ/NCHUNK)  // 64

typedef __bf16 bf16_t;
typedef __bf16 bf16x8 __attribute__((ext_vector_type(8)));
typedef __bf16 bf16x4 __attribute__((ext_vector_type(4)));
typedef float  f32x4  __attribute__((ext_vector_type(4)));

// ---------------------------------------------------------------- utilities
__device__ __forceinline__ void load_lds_128(const bf16_t* g, bf16_t* l) {
    __builtin_amdgcn_global_load_lds(
        (const __attribute__((address_space(1))) unsigned int*)g,
        (__attribute__((address_space(3))) unsigned int*)l,
        16, 0, 0);
}

__device__ __forceinline__ float2 bf16pair_to_f2(unsigned int u) {
    union { unsigned int i; float f; } a, b;
    a.i = u << 16;          // low element
    b.i = u & 0xffff0000u;  // high element
    float2 r; r.x = a.f; r.y = b.f; return r;
}

// ---------------------------------------------- fused weight convert+transpose
// all four weights in one launch; in: f32 (R,C) row-major -> out: bf16 (C,R)
__global__ __launch_bounds__(256)
void transpose_all(const float* __restrict__ gate_w, const float* __restrict__ value_w,
                   const float* __restrict__ ffn_w1, const float* __restrict__ ffn_w2,
                   bf16_t* __restrict__ wgv_t, bf16_t* __restrict__ w1_t,
                   bf16_t* __restrict__ w2_t) {
    int id = blockIdx.x;
    const float* in; bf16_t* outp; int R, C, bx, by;
    if (id < 1024)      { in = gate_w;  outp = wgv_t;               R = 1024; C = 1024; bx = id & 31;  by = id >> 5; }
    else if (id < 2048) { id -= 1024; in = value_w; outp = wgv_t + 1024*1024; R = 1024; C = 1024; bx = id & 31;  by = id >> 5; }
    else if (id < 6144) { id -= 2048; in = ffn_w1;  outp = w1_t;    R = 1024; C = 4096; bx = id & 127; by = id >> 7; }
    else                { id -= 6144; in = ffn_w2;  outp = w2_t;    R = 4096; C = 1024; bx = id & 31;  by = id >> 5; }
    __shared__ float t[32][33];
    int tx = threadIdx.x & 31, ty = threadIdx.x >> 5;   // 32 x 8
    int c0 = bx * 32, r0 = by * 32;
    #pragma unroll
    for (int j = 0; j < 32; j += 8)
        t[ty + j][tx] = in[(size_t)(r0 + ty + j) * C + c0 + tx];
    __syncthreads();
    #pragma unroll
    for (int j = 0; j < 32; j += 8)
        outp[(size_t)(c0 + ty + j) * R + r0 + tx] = (bf16_t)t[tx][ty + j];
}

// ---------------------------------------------------------------- layernorm
__global__ __launch_bounds__(256)
void ln_kernel(const float* __restrict__ x, const float* __restrict__ gamma,
               const float* __restrict__ beta, bf16_t* __restrict__ h) {
    int row = blockIdx.x;
    int tid = threadIdx.x;
    const float4* xr = (const float4*)(x + (size_t)row * D_MODEL);
    float4 v = xr[tid];
    float s  = v.x + v.y + v.z + v.w;
    float ss = v.x*v.x + v.y*v.y + v.z*v.z + v.w*v.w;
    #pragma unroll
    for (int off = 32; off; off >>= 1) {
        s  += __shfl_down(s, off);
        ss += __shfl_down(ss, off);
    }
    __shared__ float red[8];
    int wave = tid >> 6, lane = tid & 63;
    if (lane == 0) { red[wave] = s; red[4 + wave] = ss; }
    __syncthreads();
    if (tid == 0) {
        float S  = red[0] + red[1] + red[2] + red[3];
        float SS = red[4] + red[5] + red[6] + red[7];
        float mean = S * (1.0f / D_MODEL);
        float var  = SS * (1.0f / D_MODEL) - mean * mean;
        red[0] = mean;
        red[1] = rsqrtf(var + 1e-5f);
    }
    __syncthreads();
    float mean = red[0], rstd = red[1];
    float4 gv = ((const float4*)gamma)[tid];
    float4 bv = ((const float4*)beta)[tid];
    bf16x4 o;
    o[0] = (bf16_t)((v.x - mean) * rstd * gv.x + bv.x);
    o[1] = (bf16_t)((v.y - mean) * rstd * gv.y + bv.y);
    o[2] = (bf16_t)((v.z - mean) * rstd * gv.z + bv.z);
    o[3] = (bf16_t)((v.w - mean) * rstd * gv.w + bv.w);
    ((bf16x4*)h)[(size_t)row * (D_MODEL / 4) + tid] = o;
}

// ---------------------------------------------------------------- GEMM
// A: bf16 (M,K) row-major.  Bt: bf16 (N,K) row-major.
// 1-D grid with XCD-partition-by-m swizzle: hardware XCD = blockIdx % 8, so
// b(m-band) = (L&7) + 8*(r/TN), j(n-tile) = r % TN  puts all TN blocks that
// share an A m-band on ONE XCD -> each A band enters exactly one L2.
// (r3's n-major grid put one n-tile per XCD -> every XCD streamed ALL of A:
//  FETCH 570 MB on ffn2.)
// BK=64, XOR-swizzled LDS staging (zero bank conflicts, verified r2).
// MFMA operands swapped so each lane's 4 acc values are 4 consecutive n.
// __launch_bounds__(256,4): 128 unified regs -> 4 blocks/CU (verified r3).
// MODE 2: out_bf16 = gelu_exact(acc + bias)
// MODE 3: out_f32  = xres + acc + bias
// MODE 4: fused gate/value: n<1024 -> sigmoid(acc+bias) -> out; else acc+bias2 -> out2
template <int MODE, int TN>
__global__ __launch_bounds__(256, 4)
void gemm_kernel(const bf16_t* __restrict__ A, const bf16_t* __restrict__ Bt,
                 const float* __restrict__ bias, const float* __restrict__ bias2,
                 const float* __restrict__ xres,
                 void* __restrict__ out, void* __restrict__ out2,
                 int M, int N, int K) {
    __shared__ __align__(16) bf16_t ldsA[128 * 64];   // 16 KiB
    __shared__ __align__(16) bf16_t ldsB[128 * 64];   // 16 KiB

    const int tid  = threadIdx.x;
    const int lane = tid & 63;
    const int wave = tid >> 6;
    const int wm   = wave & 1;   // 2x2 wave grid, each wave 64x64
    const int wn   = wave >> 1;

    const int L  = blockIdx.x;
    const int r  = L >> 3;
    const int n0 = (r % TN) * 128;
    const int m0 = ((L & 7) + 8 * (r / TN)) * 128;

    f32x4 acc[4][4];
    f32x4 zero = {0.f, 0.f, 0.f, 0.f};
    #pragma unroll
    for (int i = 0; i < 4; i++)
        #pragma unroll
        for (int j = 0; j < 4; j++) acc[i][j] = zero;

    // staging: each issue covers 8 rows x 64 cols (8 lanes/row, 16B chunks)
    const int rl     = lane >> 3;             // row within 8-row group
    const int srcCol = ((lane & 7) ^ rl) * 8; // swizzled source col (bf16 units)

    const int quad = lane >> 4;
    const int l16  = lane & 15;
    const int rswz = l16 & 7;                 // row&7 for frag reads

    for (int k0 = 0; k0 < K; k0 += 64) {
        __syncthreads();
        #pragma unroll
        for (int i = 0; i < 4; i++) {
            int cb = i * 4 + wave;            // 16 groups of 8 rows
            int rr = cb * 8 + rl;
            load_lds_128(A  + (size_t)(m0 + rr) * K + k0 + srcCol,
                         ldsA + cb * 512 + lane * 8);
            load_lds_128(Bt + (size_t)(n0 + rr) * K + k0 + srcCol,
                         ldsB + cb * 512 + lane * 8);
        }
        __syncthreads();

        #pragma unroll
        for (int kk = 0; kk < 2; kk++) {
            int pos = ((quad + 4 * kk) ^ rswz) * 8;
            bf16x8 af[4], bfr[4];
            #pragma unroll
            for (int mt = 0; mt < 4; mt++)
                af[mt] = *(const bf16x8*)(ldsA + (wm * 64 + mt * 16 + l16) * 64 + pos);
            #pragma unroll
            for (int nt = 0; nt < 4; nt++)
                bfr[nt] = *(const bf16x8*)(ldsB + (wn * 64 + nt * 16 + l16) * 64 + pos);
            #pragma unroll
            for (int mt = 0; mt < 4; mt++)
                #pragma unroll
                for (int nt = 0; nt < 4; nt++)
                    acc[mt][nt] = __builtin_amdgcn_mfma_f32_16x16x32_bf16(
                        bfr[nt], af[mt], acc[mt][nt], 0, 0, 0);
        }
    }

    // epilogue: lane holds C[m0+wm*64+mt*16+l16][n0+wn*64+nt*16+quad*4 + r]
    #pragma unroll
    for (int mt = 0; mt < 4; mt++) {
        int row = m0 + wm * 64 + mt * 16 + l16;
        #pragma unroll
        for (int nt = 0; nt < 4; nt++) {
            int col = n0 + wn * 64 + nt * 16 + quad * 4;
            f32x4 a = acc[mt][nt];
            if (MODE == 4) {
                bool isV = (n0 >= 1024);         // block-uniform
                int c1 = col & 1023;
                float4 bv = *(const float4*)((isV ? bias2 : bias) + c1);
                float4 val;
                val.x = a[0] + bv.x; val.y = a[1] + bv.y;
                val.z = a[2] + bv.z; val.w = a[3] + bv.w;
                if (!isV) {
                    val.x = 1.0f / (1.0f + __expf(-val.x));
                    val.y = 1.0f / (1.0f + __expf(-val.y));
                    val.z = 1.0f / (1.0f + __expf(-val.z));
                    val.w = 1.0f / (1.0f + __expf(-val.w));
                }
                bf16x4 p;
                p[0] = (bf16_t)val.x; p[1] = (bf16_t)val.y;
                p[2] = (bf16_t)val.z; p[3] = (bf16_t)val.w;
                bf16_t* o = (bf16_t*)(isV ? out2 : out);
                *(bf16x4*)(o + (size_t)row * 1024 + c1) = p;
            } else if (MODE == 2) {
                float4 bv = *(const float4*)(bias + col);
                float4 val;
                val.x = a[0] + bv.x; val.y = a[1] + bv.y;
                val.z = a[2] + bv.z; val.w = a[3] + bv.w;
                val.x = 0.5f * val.x * (1.0f + erff(val.x * 0.70710678118654752f));
                val.y = 0.5f * val.y * (1.0f + erff(val.y * 0.70710678118654752f));
                val.z = 0.5f * val.z * (1.0f + erff(val.z * 0.70710678118654752f));
                val.w = 0.5f * val.w * (1.0f + erff(val.w * 0.70710678118654752f));
                bf16x4 p;
                p[0] = (bf16_t)val.x; p[1] = (bf16_t)val.y;
                p[2] = (bf16_t)val.z; p[3] = (bf16_t)val.w;
                *(bf16x4*)((bf16_t*)out + (size_t)row * N + col) = p;
            } else { // MODE 3
                float4 bv = *(const float4*)(bias + col);
                float4 xr = *(const float4*)(xres + (size_t)row * N + col);
                float4 val;
                val.x = xr.x + a[0] + bv.x; val.y = xr.y + a[1] + bv.y;
                val.z = xr.z + a[2] + bv.z; val.w = xr.w + a[3] + bv.w;
                *(float4*)((float*)out + (size_t)row * N + col) = val;
            }
        }
    }
}

// ---------------------------------------------------------------- scan
// phase A: per-chunk sums of g and g*v
__global__ __launch_bounds__(256)
void scan_partial(const bf16_t* __restrict__ g, const bf16_t* __restrict__ v,
                  float* __restrict__ sg, float* __restrict__ sgv) {
    int dt = blockIdx.x & 1;
    int c  = (blockIdx.x >> 1) & (NCHUNK - 1);
    int b  = blockIdx.x >> 7;
    int d  = dt * 512 + threadIdx.x * 2;
    float s0 = 0.f, s1 = 0.f, t0 = 0.f, t1 = 0.f;
    for (int i = 0; i < LCHUNK; i++) {
        int s = c * LCHUNK + i;
        size_t idx = ((size_t)(b * SEQ + s)) * D_MODEL + d;
        float2 gf = bf16pair_to_f2(*(const unsigned int*)(g + idx));
        float2 vf = bf16pair_to_f2(*(const unsigned int*)(v + idx));
        s0 += gf.x; s1 += gf.y;
        t0 += gf.x * vf.x; t1 += gf.y * vf.y;
    }
    size_t o = ((size_t)(b * NCHUNK + c)) * D_MODEL + d;
    sg[o] = s0;  sg[o + 1] = s1;
    sgv[o] = t0; sgv[o + 1] = t1;
}

// phase B+C fused: each block sums partials of chunks < c (2 MB, L2-resident),
// then applies x_new = x + cumsum(g*v)/(cumsum(g)+eps)
__global__ __launch_bounds__(256)
void scan_apply(const bf16_t* __restrict__ g, const bf16_t* __restrict__ v,
                const float* __restrict__ x, const float* __restrict__ sg,
                const float* __restrict__ sgv, float* __restrict__ out) {
    int dt = blockIdx.x & 1;
    int c  = (blockIdx.x >> 1) & (NCHUNK - 1);
    int b  = blockIdx.x >> 7;
    int d  = dt * 512 + threadIdx.x * 2;
    float rg0 = 0.f, rg1 = 0.f, rv0 = 0.f, rv1 = 0.f;
    for (int p = 0; p < c; p++) {
        size_t o = ((size_t)(b * NCHUNK + p)) * D_MODEL + d;
        float2 a  = *(const float2*)(sg + o);
        float2 bb = *(const float2*)(sgv + o);
        rg0 += a.x;  rg1 += a.y;
        rv0 += bb.x; rv1 += bb.y;
    }
    for (int i = 0; i < LCHUNK; i++) {
        int s = c * LCHUNK + i;
        size_t idx = ((size_t)(b * SEQ + s)) * D_MODEL + d;
        float2 gf = bf16pair_to_f2(*(const unsigned int*)(g + idx));
        float2 vf = bf16pair_to_f2(*(const unsigned int*)(v + idx));
        rv0 += gf.x * vf.x; rg0 += gf.x;
        rv1 += gf.y * vf.y; rg1 += gf.y;
        float2 xv = *(const float2*)(x + idx);
        float2 ov;
        ov.x = xv.x + rv0 / (rg0 + 1e-6f);
        ov.y = xv.y + rv1 / (rg1 + 1e-6f);
        *(float2*)(out + idx) = ov;
    }
}

// ---------------------------------------------------------------- launcher
extern "C" void kernel_launch(void* const* d_in, const int* in_sizes, int n_in,
                              void* d_out, int out_size, void* d_ws, size_t ws_size,
                              hipStream_t stream) {
    (void)in_sizes; (void)n_in; (void)out_size; (void)ws_size;
    const float* x       = (const float*)d_in[0];
    const float* ln1_g   = (const float*)d_in[1];
    const float* ln1_b   = (const float*)d_in[2];
    const float* ln2_g   = (const float*)d_in[3];
    const float* ln2_b   = (const float*)d_in[4];
    const float* gate_w  = (const float*)d_in[5];
    const float* gate_b  = (const float*)d_in[6];
    const float* value_w = (const float*)d_in[7];
    const float* value_b = (const float*)d_in[8];
    const float* ffn_w1  = (const float*)d_in[9];
    const float* ffn_b1  = (const float*)d_in[10];
    const float* ffn_w2  = (const float*)d_in[11];
    const float* ffn_b2  = (const float*)d_in[12];
    float* out = (float*)d_out;

    char* ws = (char*)d_ws;
    const size_t MB = 1024 * 1024;
    bf16_t* wgv_t = (bf16_t*)(ws + 0 * MB);     // (2048,1024) bf16   4 MB
    bf16_t* w1_t  = (bf16_t*)(ws + 4 * MB);     // (4096,1024) bf16   8 MB
    bf16_t* w2_t  = (bf16_t*)(ws + 12 * MB);    // (1024,4096) bf16   8 MB
    bf16_t* h     = (bf16_t*)(ws + 20 * MB);    // (16384,1024) bf16 32 MB (reused as h2)
    bf16_t* g     = (bf16_t*)(ws + 52 * MB);    // (16384,1024) bf16 32 MB
    bf16_t* v     = (bf16_t*)(ws + 84 * MB);    // (16384,1024) bf16 32 MB
    float*  sg    = (float*)(ws + 116 * MB);    // (4,64,1024) f32    1 MB
    float*  sgv   = (float*)(ws + 117 * MB);    // (4,64,1024) f32    1 MB
    bf16_t* act   = (bf16_t*)(ws + 118 * MB);   // (16384,4096) bf16 128 MB

    // 1. all weight transposes in one launch
    transpose_all<<<10240, 256, 0, stream>>>(gate_w, value_w, ffn_w1, ffn_w2,
                                             wgv_t, w1_t, w2_t);

    // 2. h = LN1(x)
    ln_kernel<<<M_ROWS, 256, 0, stream>>>(x, ln1_g, ln1_b, h);

    // 3. fused: g = sigmoid(h@gate_w + gate_b); v = h@value_w + value_b
    gemm_kernel<4, 16><<<(2048 / 128) * (M_ROWS / 128), 256, 0, stream>>>(
        h, wgv_t, gate_b, value_b, nullptr, g, v, M_ROWS, 2048, 1024);

    // 4. x_new = x + cumsum(g*v)/(cumsum(g)+eps)  -> d_out
    scan_partial<<<BATCH * NCHUNK * 2, 256, 0, stream>>>(g, v, sg, sgv);
    scan_apply<<<BATCH * NCHUNK * 2, 256, 0, stream>>>(g, v, x, sg, sgv, out);

    // 5. h2 = LN2(x_new)
    ln_kernel<<<M_ROWS, 256, 0, stream>>>(out, ln2_g, ln2_b, h);

    // 6. act = gelu(h2@ffn_w1 + ffn_b1)
    gemm_kernel<2, 32><<<(4096 / 128) * (M_ROWS / 128), 256, 0, stream>>>(
        h, w1_t, ffn_b1, nullptr, nullptr, act, nullptr, M_ROWS, 4096, 1024);

    // 7. out = x_new + act@ffn_w2 + ffn_b2
    gemm_kernel<3, 8><<<(1024 / 128) * (M_ROWS / 128), 256, 0, stream>>>(
        act, w2_t, ffn_b2, nullptr, out, out, nullptr, M_ROWS, 1024, 4096);
}